// Round 8
// baseline (45.315 us; speedup 1.0000x reference)
//
#include <hip/hip_runtime.h>
#include <hip/hip_bf16.h>
#include <math.h>

// MRL-E loss, B=512, D=256, C=1000.
// loss = (1/(B*D)) * sum_i [ sum_k LSE_k(i) - sum_j z[i,j]*W[y_i,j]*(D-j) ]
// No-max LSE (logit std <= 0.32); logits in log2 domain (Wtb = W^T * log2e,
// bf16) so exp is one v_exp_f32 and lse = ln2 * log2(S).
// R8 = R7's barrier-free k-loop + R5's (row x class-half) grid (1024 blocks,
// 4 blocks/CU -> 4 waves/SIMD) + z via the SCALAR pipe (wave-uniform s_load,
// keeps the vector lgkm stream pure for the wave-private LDS reduce).
// Main has ONE __syncthreads (end-of-loop 4-wave combine); finish kernel
// does log + telescoped label term + final reduction.

#define MRLE_B 512
#define MRLE_D 256
#define MRLE_C 1000
#define MRLE_CP 1024            // padded classes
#define MRLE_KROWS 264          // D + prefetch depth (pad rows: dead data)
#define MRLE_NT 256
#define ROWD (MRLE_CP / 2)      // dwords per k-row = 512
#define LOG2E 1.4426950408889634f
#define LN2   0.6931471805599453f

#if __has_builtin(__builtin_amdgcn_exp2f)
#define EXP2(x) __builtin_amdgcn_exp2f(x)
#else
#define EXP2(x) __builtin_exp2f(x)
#endif

// ---- transpose + bf16: Wtb[k][c] = bf16(W[c][k] * log2e); pad c -> 0 ------
__global__ __launch_bounds__(256) void mrle_transpose(
    const float* __restrict__ W, unsigned short* __restrict__ Wtb)
{
    __shared__ float tile[64][65];
    const int c0 = blockIdx.x * 64;
    const int k0 = blockIdx.y * 64;
    const int t  = threadIdx.x;
    const int r  = t >> 2;
    const int q  = t & 3;

#pragma unroll
    for (int j = 0; j < 4; ++j) {
        const int c    = c0 + r;
        const int kcol = q * 4 + j * 16;
        float4 v = make_float4(0.f, 0.f, 0.f, 0.f);
        if (c < MRLE_C) v = *(const float4*)&W[(size_t)c * MRLE_D + k0 + kcol];
        tile[r][kcol + 0] = v.x;
        tile[r][kcol + 1] = v.y;
        tile[r][kcol + 2] = v.z;
        tile[r][kcol + 3] = v.w;
    }
    __syncthreads();

#pragma unroll
    for (int j = 0; j < 4; ++j) {
        const int cc = q * 4 + j * 16;
        unsigned short hh[4];
#pragma unroll
        for (int e = 0; e < 4; ++e) {
            const float f = tile[cc + e][r] * LOG2E;
            unsigned int u = __float_as_uint(f);
            u = (u + 0x7FFFu + ((u >> 16) & 1u)) >> 16;   // RNE to bf16
            hh[e] = (unsigned short)u;
        }
        *(ushort4*)&Wtb[(size_t)(k0 + r) * MRLE_CP + c0 + cc] =
            make_ushort4(hh[0], hh[1], hh[2], hh[3]);
    }
}

// ---- main: block = (row i, class-half hc); 4 waves x 128 classes ----------
__global__ __launch_bounds__(MRLE_NT) void mrle_main(
    const float* __restrict__ z,              // [B, D]
    const unsigned short* __restrict__ Wtb,   // [KROWS, CP] bf16, *log2e
    float* __restrict__ Sp)                   // [2, B, D] partial sums
{
    __shared__ float red[4 * 16 * 64];     // wave-private 16x64 chunks, 16KB
    __shared__ float Sw[4 * MRLE_D];       // per-wave per-k partials, 4KB

    const int bid = blockIdx.x;
    const int i   = bid >> 1;
    const int hc  = bid & 1;
    const int t   = threadIdx.x;
    const int wv  = t >> 6;
    const int l   = t & 63;

    const float* zrow = z + (size_t)i * MRLE_D;   // wave-uniform -> s_load

    // thread t owns classes cbase, cbase+1 (one bf16-pair dword per k)
    const int cbase = hc * 512 + 2 * t;
    float l0 = (cbase     < MRLE_C) ? 0.f : -INFINITY;
    float l1 = (cbase + 1 < MRLE_C) ? 0.f : -INFINITY;

    const unsigned int* Wp = (const unsigned int*)Wtb + hc * 256 + t;

    unsigned int wbuf[8];
#pragma unroll
    for (int q = 0; q < 8; ++q) wbuf[q] = Wp[(size_t)q * ROWD];

    float* redw = red + wv * (16 * 64);
    const int khat = l & 15;        // k-slot this lane reduces per chunk
    const int q16  = l & 48;        // 16*(l>>4)

#pragma unroll 1
    for (int cb = 0; cb < 16; ++cb) {
#pragma unroll
        for (int kk = 0; kk < 16; ++kk) {
            const int k = cb * 16 + kk;
            const unsigned int w = wbuf[kk & 7];
            const float zk = zrow[k];                       // scalar pipe
            const float w0 = __uint_as_float(w << 16);
            const float w1 = __uint_as_float(w & 0xFFFF0000u);
            l0 = fmaf(zk, w0, l0);
            l1 = fmaf(zk, w1, l1);
            // rotation swizzle: slot (l+kk)&63 -> <=2-way conflict (free)
            redw[kk * 64 + ((l + kk) & 63)] = EXP2(l0) + EXP2(l1);
            wbuf[kk & 7] = Wp[(size_t)(k + 8) * ROWD];      // pad rows: dead
        }

        // wave-internal transpose reduce (lgkmcnt-ordered, NO barrier):
        // lane l sums the chunk's k-slot khat over source lanes q16..q16+15
        float s = 0.f;
#pragma unroll
        for (int u = 0; u < 16; ++u)
            s += redw[khat * 64 + ((q16 + u + khat) & 63)];
        s += __shfl_xor(s, 16);
        s += __shfl_xor(s, 32);
        if (l < 16) Sw[wv * MRLE_D + cb * 16 + khat] = s;
    }

    __syncthreads();   // the only barrier: combine 4 waves' partials

    // thread t handles k = t: partial S over this block's 512 classes
    const float S4 = (Sw[t] + Sw[MRLE_D + t]) +
                     (Sw[2 * MRLE_D + t] + Sw[3 * MRLE_D + t]);
    Sp[((size_t)hc * MRLE_B + i) * MRLE_D + t] = S4;
}

// ---- finish: per row, lse = ln2*log2(S0+S1); minus telescoped label term --
__global__ __launch_bounds__(MRLE_NT) void mrle_finish(
    const float* __restrict__ Sp,     // [2, B, D]
    const float* __restrict__ z,      // [B, D]
    const int* __restrict__ labels,   // [B]
    const float* __restrict__ W,      // [C, D]
    float* __restrict__ out)          // [1]
{
    __shared__ float wred[4];
    const int i = blockIdx.x;
    const int t = threadIdx.x;

    const float s0 = Sp[(size_t)i * MRLE_D + t];
    const float s1 = Sp[((size_t)MRLE_B + i) * MRLE_D + t];
    const float lse = LN2 * __log2f(s0 + s1);

    const int y = labels[i];
    const float lab = z[i * MRLE_D + t] * W[(size_t)y * MRLE_D + t] *
                      (float)(MRLE_D - t);

    float v = lse - lab;
#pragma unroll
    for (int d = 1; d < 64; d <<= 1) v += __shfl_xor(v, d);
    if ((t & 63) == 0) wred[t >> 6] = v;
    __syncthreads();
    if (t == 0)
        atomicAdd(out, (wred[0] + wred[1] + wred[2] + wred[3]) *
                           (1.0f / ((float)MRLE_B * (float)MRLE_D)));
}

extern "C" void kernel_launch(void* const* d_in, const int* in_sizes, int n_in,
                              void* d_out, int out_size, void* d_ws, size_t ws_size,
                              hipStream_t stream) {
    const float* z      = (const float*)d_in[0];   // [512, 256]
    const int*   labels = (const int*)d_in[1];     // [512]
    const float* W      = (const float*)d_in[2];   // [1000, 256]
    float*       out    = (float*)d_out;           // scalar

    // ws: Wtb [264][1024] bf16 = 528 KB (rows 256..263 prefetch-only),
    //     Sp  [2][512][256] f32 = 1 MB at offset 544 KB.
    unsigned short* Wtb = (unsigned short*)d_ws;
    float*          Sp  = (float*)((char*)d_ws + 544 * 1024);

    hipMemsetAsync(out, 0, sizeof(float), stream);
    mrle_transpose<<<dim3(16, 4), 256, 0, stream>>>(W, Wtb);
    mrle_main<<<MRLE_B * 2, MRLE_NT, 0, stream>>>(z, Wtb, Sp);
    mrle_finish<<<MRLE_B, MRLE_NT, 0, stream>>>(Sp, z, labels, W, out);
}

// Round 9
// 39.371 us; speedup vs baseline: 1.1510x; 1.1510x over previous
//
#include <hip/hip_runtime.h>
#include <hip/hip_bf16.h>
#include <math.h>

// MRL-E loss, B=512, D=256, C=1000.
// loss = (1/(B*D)) * sum_i [ sum_k LSE_k(i) - sum_j z[i,j]*W[y_i,j]*(D-j) ]
// No-max LSE (logit std <= 0.32); logits in log2 domain (Wtb = W^T * log2e,
// bf16) so exp is one v_exp_f32 and lse = ln2 * log2(S).
// R9 = R7's single-dispatch barrier-free skeleton at 8 waves/block:
// one block per row, 512 threads; wave w owns classes [128w, 128w+128)
// (2/lane, one bf16-pair dword per k). 4 waves/SIMD (2x R7's TLP).
// Per-16k chunk: z preloaded to registers (4x uniform ds_read_b128), inner
// loop's only DS op is the redw write; wave-private rotation-swizzled
// transpose reduce (<=2-way, free), ordered by lgkmcnt only — NO barrier in
// the k-loop. One end barrier combines 8 waves; log + telescoped label term
// + atomic finish in-kernel.

#define MRLE_B 512
#define MRLE_D 256
#define MRLE_C 1000
#define MRLE_CP 1024            // padded classes
#define MRLE_KROWS 264          // D + prefetch depth (pad rows: dead data)
#define MRLE_NT 512
#define ROWD (MRLE_CP / 2)      // dwords per k-row = 512
#define LOG2E 1.4426950408889634f
#define LN2   0.6931471805599453f

#if __has_builtin(__builtin_amdgcn_exp2f)
#define EXP2(x) __builtin_amdgcn_exp2f(x)
#else
#define EXP2(x) __builtin_exp2f(x)
#endif

// ---- transpose + bf16: Wtb[k][c] = bf16(W[c][k] * log2e); pad c -> 0 ------
__global__ __launch_bounds__(256) void mrle_transpose(
    const float* __restrict__ W, unsigned short* __restrict__ Wtb)
{
    __shared__ float tile[64][65];
    const int c0 = blockIdx.x * 64;
    const int k0 = blockIdx.y * 64;
    const int t  = threadIdx.x;
    const int r  = t >> 2;
    const int q  = t & 3;

#pragma unroll
    for (int j = 0; j < 4; ++j) {
        const int c    = c0 + r;
        const int kcol = q * 4 + j * 16;
        float4 v = make_float4(0.f, 0.f, 0.f, 0.f);
        if (c < MRLE_C) v = *(const float4*)&W[(size_t)c * MRLE_D + k0 + kcol];
        tile[r][kcol + 0] = v.x;
        tile[r][kcol + 1] = v.y;
        tile[r][kcol + 2] = v.z;
        tile[r][kcol + 3] = v.w;
    }
    __syncthreads();

#pragma unroll
    for (int j = 0; j < 4; ++j) {
        const int cc = q * 4 + j * 16;
        unsigned short hh[4];
#pragma unroll
        for (int e = 0; e < 4; ++e) {
            const float f = tile[cc + e][r] * LOG2E;
            unsigned int u = __float_as_uint(f);
            u = (u + 0x7FFFu + ((u >> 16) & 1u)) >> 16;   // RNE to bf16
            hh[e] = (unsigned short)u;
        }
        *(ushort4*)&Wtb[(size_t)(k0 + r) * MRLE_CP + c0 + cc] =
            make_ushort4(hh[0], hh[1], hh[2], hh[3]);
    }
}

// ---- main: one block per row; 8 waves x 128 classes each ------------------
__global__ __launch_bounds__(MRLE_NT) void mrle_main(
    const float* __restrict__ z,              // [B, D]
    const int* __restrict__ labels,           // [B]
    const float* __restrict__ W,              // [C, D] (label term)
    const unsigned short* __restrict__ Wtb,   // [KROWS, CP] bf16, *log2e
    float* __restrict__ out)                  // [1]
{
    __shared__ float zsh[MRLE_D];          // raw z row (1 KB)
    __shared__ float red[8 * 16 * 64];     // wave-private 16x64 chunks, 32 KB
    __shared__ float Sw[8 * MRLE_D];       // per-wave per-k partials, 8 KB
    __shared__ float wred[8];

    const int i  = blockIdx.x;
    const int t  = threadIdx.x;
    const int wv = t >> 6;
    const int l  = t & 63;

    if (t < MRLE_D) zsh[t] = z[i * MRLE_D + t];
    __syncthreads();   // the only barrier before the tail

    // thread t owns classes 2t, 2t+1 (t >= 500 -> all pad, -inf logits)
    const int cbase = 2 * t;
    float l0 = (cbase     < MRLE_C) ? 0.f : -INFINITY;
    float l1 = (cbase + 1 < MRLE_C) ? 0.f : -INFINITY;

    const unsigned int* Wp = (const unsigned int*)Wtb + t;

    unsigned int wbuf[8];
#pragma unroll
    for (int q = 0; q < 8; ++q) wbuf[q] = Wp[(size_t)q * ROWD];

    float* redw = red + wv * (16 * 64);
    const int khat = l & 15;        // k-slot this lane reduces per chunk
    const int q16  = l & 48;        // 16*(l>>4)

#pragma unroll 1
    for (int cb = 0; cb < 16; ++cb) {
        // preload this chunk's 16 z values (uniform addr -> LDS broadcast)
        float zq[16];
        *(float4*)&zq[0]  = *(const float4*)&zsh[cb * 16 + 0];
        *(float4*)&zq[4]  = *(const float4*)&zsh[cb * 16 + 4];
        *(float4*)&zq[8]  = *(const float4*)&zsh[cb * 16 + 8];
        *(float4*)&zq[12] = *(const float4*)&zsh[cb * 16 + 12];

#pragma unroll
        for (int kk = 0; kk < 16; ++kk) {
            const int k = cb * 16 + kk;
            const unsigned int w = wbuf[kk & 7];
            const float w0 = __uint_as_float(w << 16);
            const float w1 = __uint_as_float(w & 0xFFFF0000u);
            l0 = fmaf(zq[kk], w0, l0);
            l1 = fmaf(zq[kk], w1, l1);
            // rotation swizzle: slot (l+kk)&63 -> <=2-way conflict (free)
            redw[kk * 64 + ((l + kk) & 63)] = EXP2(l0) + EXP2(l1);
            wbuf[kk & 7] = Wp[(size_t)(k + 8) * ROWD];   // pad rows: dead
        }

        // wave-internal transpose reduce (lgkmcnt-ordered, NO barrier):
        // lane l sums the chunk's k-slot khat over source lanes q16..q16+15
        float s = 0.f;
#pragma unroll
        for (int u = 0; u < 16; ++u)
            s += redw[khat * 64 + ((q16 + u + khat) & 63)];
        s += __shfl_xor(s, 16);
        s += __shfl_xor(s, 32);
        if (l < 16) Sw[wv * MRLE_D + cb * 16 + khat] = s;
    }

    __syncthreads();   // combine the 8 waves' partials

    float v = 0.f;
    if (t < MRLE_D) {
        // thread t handles step k = t: total S, lse = ln2 * log2(S)
        float S = 0.f;
#pragma unroll
        for (int wq = 0; wq < 8; ++wq) S += Sw[wq * MRLE_D + t];
        const float lse = LN2 * __log2f(S);

        // telescoped label term: thread t handles feature j = t
        const int y = labels[i];
        const float lab = zsh[t] * W[(size_t)y * MRLE_D + t] *
                          (float)(MRLE_D - t);
        v = lse - lab;
    }

#pragma unroll
    for (int d = 1; d < 64; d <<= 1) v += __shfl_xor(v, d);
    if (l == 0) wred[wv] = v;
    __syncthreads();
    if (t == 0) {
        float tot = 0.f;
#pragma unroll
        for (int wq = 0; wq < 8; ++wq) tot += wred[wq];
        atomicAdd(out, tot * (1.0f / ((float)MRLE_B * (float)MRLE_D)));
    }
}

extern "C" void kernel_launch(void* const* d_in, const int* in_sizes, int n_in,
                              void* d_out, int out_size, void* d_ws, size_t ws_size,
                              hipStream_t stream) {
    const float* z      = (const float*)d_in[0];   // [512, 256]
    const int*   labels = (const int*)d_in[1];     // [512]
    const float* W      = (const float*)d_in[2];   // [1000, 256]
    float*       out    = (float*)d_out;           // scalar

    // ws: Wtb [264][1024] bf16 = 528 KB; rows 256..263 prefetched, never used
    unsigned short* Wtb = (unsigned short*)d_ws;

    hipMemsetAsync(out, 0, sizeof(float), stream);
    mrle_transpose<<<dim3(16, 4), 256, 0, stream>>>(W, Wtb);
    mrle_main<<<MRLE_B, MRLE_NT, 0, stream>>>(z, labels, W, Wtb, out);
}

// Round 10
// 38.218 us; speedup vs baseline: 1.1857x; 1.0302x over previous
//
#include <hip/hip_runtime.h>
#include <hip/hip_bf16.h>
#include <math.h>

// MRL-E loss, B=512, D=256, C=1000.
// loss = (1/(B*D)) * sum_i [ sum_k LSE_k(i) - sum_j z[i,j]*W[y_i,j]*(D-j) ]
// No-max LSE (logit std <= 0.32); logits in log2 domain (Wtb = W^T * log2e,
// bf16) so exp is one v_exp_f32 and lse = ln2 * log2(S).
// R10 = R9 skeleton (1 block/row, 8 waves, barrier-free k-loop, wave-private
// deferred reduce) with a VALU DIET:
//  - redw layout slot = srclane*17 + kk: write addr = l*17 (fixed) + imm kk,
//    read addr = q16*17+khat (fixed) + imm u -> ZERO addressing VALU in the
//    reduce; both sides <=2-way bank aliasing (free).
//  - global prefetch through 4 centered pointers per chunk so every load
//    folds to a +-4096B imm offset (8 VALU/chunk vs 32).

#define MRLE_B 512
#define MRLE_D 256
#define MRLE_C 1000
#define MRLE_CP 1024            // padded classes
#define MRLE_KROWS 264          // D + prefetch depth (pad rows: dead data)
#define MRLE_NT 512
#define ROWD (MRLE_CP / 2)      // dwords per k-row = 512
#define RSTR 17                 // redw lane stride (floats)
#define LOG2E 1.4426950408889634f
#define LN2   0.6931471805599453f

#if __has_builtin(__builtin_amdgcn_exp2f)
#define EXP2(x) __builtin_amdgcn_exp2f(x)
#else
#define EXP2(x) __builtin_exp2f(x)
#endif

// ---- transpose + bf16: Wtb[k][c] = bf16(W[c][k] * log2e); pad c -> 0 ------
__global__ __launch_bounds__(256) void mrle_transpose(
    const float* __restrict__ W, unsigned short* __restrict__ Wtb)
{
    __shared__ float tile[64][65];
    const int c0 = blockIdx.x * 64;
    const int k0 = blockIdx.y * 64;
    const int t  = threadIdx.x;
    const int r  = t >> 2;
    const int q  = t & 3;

#pragma unroll
    for (int j = 0; j < 4; ++j) {
        const int c    = c0 + r;
        const int kcol = q * 4 + j * 16;
        float4 v = make_float4(0.f, 0.f, 0.f, 0.f);
        if (c < MRLE_C) v = *(const float4*)&W[(size_t)c * MRLE_D + k0 + kcol];
        tile[r][kcol + 0] = v.x;
        tile[r][kcol + 1] = v.y;
        tile[r][kcol + 2] = v.z;
        tile[r][kcol + 3] = v.w;
    }
    __syncthreads();

#pragma unroll
    for (int j = 0; j < 4; ++j) {
        const int cc = q * 4 + j * 16;
        unsigned short hh[4];
#pragma unroll
        for (int e = 0; e < 4; ++e) {
            const float f = tile[cc + e][r] * LOG2E;
            unsigned int u = __float_as_uint(f);
            u = (u + 0x7FFFu + ((u >> 16) & 1u)) >> 16;   // RNE to bf16
            hh[e] = (unsigned short)u;
        }
        *(ushort4*)&Wtb[(size_t)(k0 + r) * MRLE_CP + c0 + cc] =
            make_ushort4(hh[0], hh[1], hh[2], hh[3]);
    }
}

// ---- main: one block per row; 8 waves x 128 classes each ------------------
__global__ __launch_bounds__(MRLE_NT) void mrle_main(
    const float* __restrict__ z,              // [B, D]
    const int* __restrict__ labels,           // [B]
    const float* __restrict__ W,              // [C, D] (label term)
    const unsigned short* __restrict__ Wtb,   // [KROWS, CP] bf16, *log2e
    float* __restrict__ out)                  // [1]
{
    __shared__ float zsh[MRLE_D];            // raw z row (1 KB)
    __shared__ float red[8 * 64 * RSTR];     // wave-private, 34 KB
    __shared__ float Sw[8 * MRLE_D];         // per-wave per-k partials, 8 KB
    __shared__ float wred[8];

    const int i  = blockIdx.x;
    const int t  = threadIdx.x;
    const int wv = t >> 6;
    const int l  = t & 63;

    if (t < MRLE_D) zsh[t] = z[i * MRLE_D + t];
    __syncthreads();   // the only barrier before the tail

    // thread t owns classes 2t, 2t+1 (t >= 500 -> all pad, -inf logits)
    const int cbase = 2 * t;
    float l0 = (cbase     < MRLE_C) ? 0.f : -INFINITY;
    float l1 = (cbase + 1 < MRLE_C) ? 0.f : -INFINITY;

    const unsigned int* Wp = (const unsigned int*)Wtb + t;

    unsigned int wbuf[8];
#pragma unroll
    for (int q = 0; q < 8; ++q) wbuf[q] = Wp[(size_t)q * ROWD];

    // fixed per-lane LDS bases; all in-loop DS addresses are imm offsets
    float* redw = red + wv * (64 * RSTR);
    float* wr = redw + l * RSTR;                         // write base
    const float* rd = redw + (l & 48) * RSTR + (l & 15); // read base

#pragma unroll 1
    for (int cb = 0; cb < 16; ++cb) {
        // preload this chunk's 16 z values (uniform addr -> LDS broadcast)
        float zq[16];
        *(float4*)&zq[0]  = *(const float4*)&zsh[cb * 16 + 0];
        *(float4*)&zq[4]  = *(const float4*)&zsh[cb * 16 + 4];
        *(float4*)&zq[8]  = *(const float4*)&zsh[cb * 16 + 8];
        *(float4*)&zq[12] = *(const float4*)&zsh[cb * 16 + 12];

#pragma unroll
        for (int kk4 = 0; kk4 < 4; ++kk4) {
            // centered pointer: loads fold to imm offsets {-4096,-2048,0,2048}
            const unsigned int* qp =
                Wp + (size_t)(cb * 16 + kk4 * 4 + 10) * ROWD;
#pragma unroll
            for (int j = 0; j < 4; ++j) {
                const int kk = kk4 * 4 + j;
                const unsigned int w = wbuf[kk & 7];
                const float w0 = __uint_as_float(w << 16);
                const float w1 = __uint_as_float(w & 0xFFFF0000u);
                l0 = fmaf(zq[kk], w0, l0);
                l1 = fmaf(zq[kk], w1, l1);
                wr[kk] = EXP2(l0) + EXP2(l1);          // imm-offset ds_write
                wbuf[kk & 7] = qp[(j - 2) * (int)ROWD]; // imm-offset load
            }
        }

        // wave-internal deferred reduce (lgkmcnt-ordered, NO barrier):
        // lane l sums k-slot khat=l&15 over source lanes q16..q16+15
        float s = 0.f;
#pragma unroll
        for (int u = 0; u < 16; ++u)
            s += rd[u * RSTR];                         // imm-offset ds_read
        s += __shfl_xor(s, 16);
        s += __shfl_xor(s, 32);
        if (l < 16) Sw[wv * MRLE_D + cb * 16 + l] = s;
    }

    __syncthreads();   // combine the 8 waves' partials

    float v = 0.f;
    if (t < MRLE_D) {
        // thread t handles step k = t: total S, lse = ln2 * log2(S)
        float S = 0.f;
#pragma unroll
        for (int wq = 0; wq < 8; ++wq) S += Sw[wq * MRLE_D + t];
        const float lse = LN2 * __log2f(S);

        // telescoped label term: thread t handles feature j = t
        const int y = labels[i];
        const float lab = zsh[t] * W[(size_t)y * MRLE_D + t] *
                          (float)(MRLE_D - t);
        v = lse - lab;
    }

#pragma unroll
    for (int d = 1; d < 64; d <<= 1) v += __shfl_xor(v, d);
    if (l == 0) wred[wv] = v;
    __syncthreads();
    if (t == 0) {
        float tot = 0.f;
#pragma unroll
        for (int wq = 0; wq < 8; ++wq) tot += wred[wq];
        atomicAdd(out, tot * (1.0f / ((float)MRLE_B * (float)MRLE_D)));
    }
}

extern "C" void kernel_launch(void* const* d_in, const int* in_sizes, int n_in,
                              void* d_out, int out_size, void* d_ws, size_t ws_size,
                              hipStream_t stream) {
    const float* z      = (const float*)d_in[0];   // [512, 256]
    const int*   labels = (const int*)d_in[1];     // [512]
    const float* W      = (const float*)d_in[2];   // [1000, 256]
    float*       out    = (float*)d_out;           // scalar

    // ws: Wtb [264][1024] bf16 = 528 KB; rows 256..263 prefetched, never used
    unsigned short* Wtb = (unsigned short*)d_ws;

    hipMemsetAsync(out, 0, sizeof(float), stream);
    mrle_transpose<<<dim3(16, 4), 256, 0, stream>>>(W, Wtb);
    mrle_main<<<MRLE_B, MRLE_NT, 0, stream>>>(z, labels, W, Wtb, out);
}

// Round 11
// 35.583 us; speedup vs baseline: 1.2735x; 1.0740x over previous
//
#include <hip/hip_runtime.h>
#include <hip/hip_bf16.h>
#include <math.h>

// MRL-E loss, B=512, D=256, C=1000.
// loss = (1/(B*D)) * sum_i [ sum_k LSE_k(i) - sum_j z[i,j]*W[y_i,j]*(D-j) ]
// No-max LSE (logit std <= 0.32); logits in log2 domain (Wtb = W^T * log2e,
// bf16) so exp is one v_exp_f32 and lse = ln2 * log2(S).
// R11 = R10 + (1) software-pipelined chunk reduce: chunk cb-1's 16 ds_reads
// issue BEFORE chunk cb's compute (in-order DS per wave: reads beat the
// overwriting writes), sum/shfl/store after — reduce latency hides under
// fma/exp; (2) memset dispatch removed (transpose zeroes out); (3) odd-class
// weight consumed as asfloat(w) directly (mantissa-noise < bf16 quant step),
// saving the v_and per step.

#define MRLE_B 512
#define MRLE_D 256
#define MRLE_C 1000
#define MRLE_CP 1024            // padded classes
#define MRLE_KROWS 264          // D + prefetch depth (pad rows: dead data)
#define MRLE_NT 512
#define ROWD (MRLE_CP / 2)      // dwords per k-row = 512
#define RSTR 17                 // redw lane stride (floats)
#define LOG2E 1.4426950408889634f
#define LN2   0.6931471805599453f

#if __has_builtin(__builtin_amdgcn_exp2f)
#define EXP2(x) __builtin_amdgcn_exp2f(x)
#else
#define EXP2(x) __builtin_exp2f(x)
#endif

// ---- transpose + bf16: Wtb[k][c] = bf16(W[c][k] * log2e); pad c -> 0 ------
// Also zeroes the output scalar (replaces a separate memset dispatch).
__global__ __launch_bounds__(256) void mrle_transpose(
    const float* __restrict__ W, unsigned short* __restrict__ Wtb,
    float* __restrict__ out)
{
    __shared__ float tile[64][65];
    const int c0 = blockIdx.x * 64;
    const int k0 = blockIdx.y * 64;
    const int t  = threadIdx.x;
    const int r  = t >> 2;
    const int q  = t & 3;

    if (c0 == 0 && k0 == 0 && t == 0) out[0] = 0.f;   // stream-ordered init

#pragma unroll
    for (int j = 0; j < 4; ++j) {
        const int c    = c0 + r;
        const int kcol = q * 4 + j * 16;
        float4 v = make_float4(0.f, 0.f, 0.f, 0.f);
        if (c < MRLE_C) v = *(const float4*)&W[(size_t)c * MRLE_D + k0 + kcol];
        tile[r][kcol + 0] = v.x;
        tile[r][kcol + 1] = v.y;
        tile[r][kcol + 2] = v.z;
        tile[r][kcol + 3] = v.w;
    }
    __syncthreads();

#pragma unroll
    for (int j = 0; j < 4; ++j) {
        const int cc = q * 4 + j * 16;
        unsigned short hh[4];
#pragma unroll
        for (int e = 0; e < 4; ++e) {
            const float f = tile[cc + e][r] * LOG2E;
            unsigned int u = __float_as_uint(f);
            u = (u + 0x7FFFu + ((u >> 16) & 1u)) >> 16;   // RNE to bf16
            hh[e] = (unsigned short)u;
        }
        *(ushort4*)&Wtb[(size_t)(k0 + r) * MRLE_CP + c0 + cc] =
            make_ushort4(hh[0], hh[1], hh[2], hh[3]);
    }
}

// ---- main: one block per row; 8 waves x 128 classes each ------------------
__global__ __launch_bounds__(MRLE_NT) void mrle_main(
    const float* __restrict__ z,              // [B, D]
    const int* __restrict__ labels,           // [B]
    const float* __restrict__ W,              // [C, D] (label term)
    const unsigned short* __restrict__ Wtb,   // [KROWS, CP] bf16, *log2e
    float* __restrict__ out)                  // [1]
{
    __shared__ float zsh[MRLE_D];            // raw z row (1 KB)
    __shared__ float red[8 * 64 * RSTR];     // wave-private, 34 KB
    __shared__ float Sw[8 * MRLE_D];         // per-wave per-k partials, 8 KB
    __shared__ float wred[8];

    const int i  = blockIdx.x;
    const int t  = threadIdx.x;
    const int wv = t >> 6;
    const int l  = t & 63;

    if (t < MRLE_D) zsh[t] = z[i * MRLE_D + t];
    __syncthreads();   // the only barrier before the tail

    // thread t owns classes 2t, 2t+1 (t >= 500 -> all pad, -inf logits)
    const int cbase = 2 * t;
    float l0 = (cbase     < MRLE_C) ? 0.f : -INFINITY;
    float l1 = (cbase + 1 < MRLE_C) ? 0.f : -INFINITY;

    const unsigned int* Wp = (const unsigned int*)Wtb + t;

    unsigned int wbuf[8];
#pragma unroll
    for (int q = 0; q < 8; ++q) wbuf[q] = Wp[(size_t)q * ROWD];

    // fixed per-lane LDS bases; all in-loop DS addresses are imm offsets
    float* redw = red + wv * (64 * RSTR);
    float* wr = redw + l * RSTR;                         // write base
    const float* rd = redw + (l & 48) * RSTR + (l & 15); // read base

#pragma unroll 1
    for (int cb = 0; cb < 16; ++cb) {
        // (A) software-pipelined reduce, part 1: issue chunk cb-1's reads
        // BEFORE this chunk's writes (in-order DS: reads beat overwrites)
        float r[16];
        if (cb > 0) {
#pragma unroll
            for (int u = 0; u < 16; ++u) r[u] = rd[u * RSTR];
        }

        // preload this chunk's 16 z values (uniform addr -> LDS broadcast)
        float zq[16];
        *(float4*)&zq[0]  = *(const float4*)&zsh[cb * 16 + 0];
        *(float4*)&zq[4]  = *(const float4*)&zsh[cb * 16 + 4];
        *(float4*)&zq[8]  = *(const float4*)&zsh[cb * 16 + 8];
        *(float4*)&zq[12] = *(const float4*)&zsh[cb * 16 + 12];

        // (B) chunk cb compute: fma/exp/ds_write + 8-deep linear prefetch
#pragma unroll
        for (int kk4 = 0; kk4 < 4; ++kk4) {
            // centered pointer: loads fold to imm offsets {-4096,...,2048}
            const unsigned int* qp =
                Wp + (size_t)(cb * 16 + kk4 * 4 + 10) * ROWD;
#pragma unroll
            for (int j = 0; j < 4; ++j) {
                const int kk = kk4 * 4 + j;
                const unsigned int w = wbuf[kk & 7];
                const float w0 = __uint_as_float(w << 16);       // even class
                const float w1 = __uint_as_float(w);             // odd: bf16
                l0 = fmaf(zq[kk], w0, l0);   // + mantissa noise < bf16 quant
                l1 = fmaf(zq[kk], w1, l1);
                wr[kk] = EXP2(l0) + EXP2(l1);          // imm-offset ds_write
                wbuf[kk & 7] = qp[(j - 2) * (int)ROWD]; // imm-offset load
            }
        }

        // (C) pipelined reduce, part 2: finish chunk cb-1 (reads landed
        // during (B)); lane l owns k-slot l&15 over source lanes l&48..+15
        if (cb > 0) {
            float s = 0.f;
#pragma unroll
            for (int u = 0; u < 16; ++u) s += r[u];
            s += __shfl_xor(s, 16);
            s += __shfl_xor(s, 32);
            if (l < 16) Sw[wv * MRLE_D + (cb - 1) * 16 + l] = s;
        }
    }

    // epilogue: reduce the last chunk (cb = 15)
    {
        float s = 0.f;
#pragma unroll
        for (int u = 0; u < 16; ++u) s += rd[u * RSTR];
        s += __shfl_xor(s, 16);
        s += __shfl_xor(s, 32);
        if (l < 16) Sw[wv * MRLE_D + 15 * 16 + l] = s;
    }

    __syncthreads();   // combine the 8 waves' partials

    float v = 0.f;
    if (t < MRLE_D) {
        // thread t handles step k = t: total S, lse = ln2 * log2(S)
        float S = 0.f;
#pragma unroll
        for (int wq = 0; wq < 8; ++wq) S += Sw[wq * MRLE_D + t];
        const float lse = LN2 * __log2f(S);

        // telescoped label term: thread t handles feature j = t
        const int y = labels[i];
        const float lab = zsh[t] * W[(size_t)y * MRLE_D + t] *
                          (float)(MRLE_D - t);
        v = lse - lab;
    }

#pragma unroll
    for (int d = 1; d < 64; d <<= 1) v += __shfl_xor(v, d);
    if (l == 0) wred[wv] = v;
    __syncthreads();
    if (t == 0) {
        float tot = 0.f;
#pragma unroll
        for (int wq = 0; wq < 8; ++wq) tot += wred[wq];
        atomicAdd(out, tot * (1.0f / ((float)MRLE_B * (float)MRLE_D)));
    }
}

extern "C" void kernel_launch(void* const* d_in, const int* in_sizes, int n_in,
                              void* d_out, int out_size, void* d_ws, size_t ws_size,
                              hipStream_t stream) {
    const float* z      = (const float*)d_in[0];   // [512, 256]
    const int*   labels = (const int*)d_in[1];     // [512]
    const float* W      = (const float*)d_in[2];   // [1000, 256]
    float*       out    = (float*)d_out;           // scalar

    // ws: Wtb [264][1024] bf16 = 528 KB; rows 256..263 prefetched, never used
    unsigned short* Wtb = (unsigned short*)d_ws;

    mrle_transpose<<<dim3(16, 4), 256, 0, stream>>>(W, Wtb, out);
    mrle_main<<<MRLE_B, MRLE_NT, 0, stream>>>(z, labels, W, Wtb, out);
}